// Round 1
// baseline (3596.560 us; speedup 1.0000x reference)
//
#include <hip/hip_runtime.h>
#include <hip/hip_bf16.h>

typedef __hip_bfloat16 bf16;
typedef __attribute__((ext_vector_type(8))) short s16x8;
typedef __attribute__((ext_vector_type(4))) float f32x4;

// Problem constants
#define TT 55
#define BB 512
#define CC 512
#define DD 512
#define KK 64
#define NCH 4                    // steps per x-precompute chunk (power of 2)
#define NXS 8                    // x-ring slots (ping-pong of NCH)
#define NHS 8                    // Hall ring slots
#define LDH ((long)NHS*1536)     // Hall ring row stride
#define XW 6400L                 // XGR row width

typedef const __attribute__((address_space(1))) unsigned int gu32;
typedef __attribute__((address_space(3))) unsigned int lu32;
__device__ __forceinline__ void gload16(const void* g, void* l) {
  __builtin_amdgcn_global_load_lds((gu32*)g, (lu32*)l, 16, 0, 0);
}

struct Seg {
  void*  dst;          // destination base (float* or bf16* per mode)
  long   ldd;          // row stride (elements)
  int    col_begin;    // inclusive (GEMM N space), 64-aligned, sorted asc
  int    mode;         // 0 = f32 store (+bias), 1 = f32 +=, 2 = bf16 store (+bias)
  const float* bias;   // indexed by (col - col_begin), may be null
};
struct SegList { Seg s[8]; int n; };

struct GDesc {
  const bf16* A; const bf16* B;
  long lda, ldb;
  int mtiles, ntiles, tile_beg, order, K;  // order: 0=nt-fast, 1=mt-fast, 2=banded(32 mt x all nt)
  SegList segs;
};
struct GArgs { GDesc g[6]; int ng; int total; int chunk; };

// ---------------- batched GEMM: C[seg] (+)= A[MxK] * B^T[NxK], bf16 in, fp32 acc
// 64x128 tile (MxN), BK=64, 4 waves (2x2 of 32x64), global_load_lds staging with
// XOR-swizzled LDS layout (block p of row r holds global block p^(r&7)).
__global__ __launch_bounds__(256) void gemm_batched(GArgs args)
{
  __shared__ __align__(16) bf16 As[64][64];    // 8 KB
  __shared__ __align__(16) bf16 Bs[128][64];   // 16 KB

  // XCD-aware: bid%8 ~ XCD; each XCD gets a contiguous tile chunk.
  int tile = (int)(blockIdx.x & 7) * args.chunk + (int)(blockIdx.x >> 3);
  if (tile >= args.total) return;

  int gi = 0;
  for (int i = 1; i < args.ng; ++i) if (tile >= args.g[i].tile_beg) gi = i;
  const GDesc& g = args.g[gi];
  const int local = tile - g.tile_beg;
  int mt, nt;
  if (g.order == 1)      { mt = local % g.mtiles; nt = local / g.mtiles; }
  else if (g.order == 2) { int band = local / (32*g.ntiles); int rem = local % (32*g.ntiles);
                           nt = rem % g.ntiles; mt = band*32 + rem / g.ntiles; }
  else                   { nt = local % g.ntiles; mt = local / g.ntiles; }

  const int tid  = threadIdx.x;
  const int wave = tid >> 6, lane = tid & 63;
  const int q = lane >> 4, mm = lane & 15;
  const int s7 = mm & 7;
  const int wm = wave >> 1, wn = wave & 1;
  const long m0 = (long)mt * 64;
  const long n0 = (long)nt * 128;

  const bf16* Ab = g.A + m0 * g.lda;
  const bf16* Bb = g.B + n0 * g.ldb;
  const long lda = g.lda, ldb = g.ldb;
  const int l8 = lane >> 3;                 // row within 8-row staging group
  const int gc = ((lane & 7) ^ l8) << 3;    // swizzled global col (elements)

  f32x4 acc[2][4] = {};

  for (int k0 = 0; k0 < g.K; k0 += 64) {
#pragma unroll
    for (int p = 0; p < 2; ++p) {
      int r = p*32 + wave*8;
      gload16(Ab + (long)(r + l8)*lda + k0 + gc, &As[r][0]);
    }
#pragma unroll
    for (int p = 0; p < 4; ++p) {
      int r = p*32 + wave*8;
      gload16(Bb + (long)(r + l8)*ldb + k0 + gc, &Bs[r][0]);
    }
    __syncthreads();
#pragma unroll
    for (int kk = 0; kk < 64; kk += 32) {
      const int pc = ((((kk >> 3) + q) ^ s7) << 3);  // physical col of logical kk+q*8
      s16x8 av[2], bv[4];
#pragma unroll
      for (int i = 0; i < 2; ++i) av[i] = *(const s16x8*)&As[wm*32 + i*16 + mm][pc];
#pragma unroll
      for (int j = 0; j < 4; ++j) bv[j] = *(const s16x8*)&Bs[wn*64 + j*16 + mm][pc];
#pragma unroll
      for (int i = 0; i < 2; ++i)
#pragma unroll
        for (int j = 0; j < 4; ++j)
          acc[i][j] = __builtin_amdgcn_mfma_f32_16x16x32_bf16(av[i], bv[j], acc[i][j], 0,0,0);
    }
    __syncthreads();
  }

  // epilogue: segment lookup per 16-col group (boundaries are 64-aligned)
#pragma unroll
  for (int j = 0; j < 4; ++j) {
    int colbase = (int)n0 + wn*64 + j*16;
    Seg sg = g.segs.s[0];
    for (int i = 1; i < g.segs.n; ++i)
      if (colbase >= g.segs.s[i].col_begin) sg = g.segs.s[i];
    int dcol = colbase + mm - sg.col_begin;
    float bv = sg.bias ? sg.bias[dcol] : 0.0f;
#pragma unroll
    for (int i = 0; i < 2; ++i) {
      f32x4 a = acc[i][j];
#pragma unroll
      for (int r = 0; r < 4; ++r) {
        long row = m0 + wm*32 + i*16 + q*4 + r;  // C/D: col=lane&15, row=q*4+reg
        long off = row * sg.ldd + dcol;
        if (sg.mode == 1)      ((float*)sg.dst)[off] += a[r];
        else if (sg.mode == 2) ((bf16*)sg.dst)[off] = __float2bfloat16(a[r] + bv);
        else                   ((float*)sg.dst)[off] = a[r] + bv;
      }
    }
  }
}

// ---------------- batched cell update: up to 3 independent (step,layer) cells
struct CellDesc {
  const void* xg;      // x-driven gate part (row stride XW), fp32 or bf16 per xbf
  const void* xr;      // x-driven gr part (row stride XW)
  int xbf;             // 1 = xg/xr are bf16, 0 = fp32
  const float* gate;   // fp32 ring [512][2048]
  const float* gate2;  // extra addend (whb ring), may be null
  const float* gate3;  // extra addend (g2b ring), may be null
  const float* gr;     // fp32 [512][64], may be null
  const float* u0;     // may be null
  const float* u1;     // may be null
  float* c;            // [512][512]
  float* d;            // [512][64]
  bf16*  hout;         // row stride LDH
};
struct CArgs { CellDesc e[3]; int n; };

__device__ inline float sigm(float x){ return 1.0f/(1.0f + __expf(-x)); }
__device__ inline float ftanh(float x){ float e = __expf(2.0f*x); return 1.0f - 2.0f/(e + 1.0f); }

// 2 batch rows per block, grid (256, n) -> 4x the blocks of the old version for latency hiding.
__global__ __launch_bounds__(256) void cell_batched(CArgs a, const float* __restrict__ wd)
{
  const CellDesc e = a.e[blockIdx.y];
  const int tid = threadIdx.x;
  const int r0 = blockIdx.x * 2;
  __shared__ float dn[2][64];

  if (tid < 128) {
    int r = tid >> 6, k = tid & 63;
    long row = r0 + r;
    float gv = e.xbf ? __bfloat162float(((const bf16*)e.xr)[row*XW + k])
                     : ((const float*)e.xr)[row*XW + k];
    if (e.gr) gv += e.gr[row*64 + k];
    if (e.u0) gv += (1.0f/3.0f)*e.u0[row*64 + k];
    if (e.u1) gv += (1.0f/3.0f)*e.u1[row*64 + k];
    float rr = sigm(gv);
    float dv = rr * e.d[row*64 + k];
    e.d[row*64 + k] = dv;
    dn[r][k] = dv;
  }
  __syncthreads();

  float accv[2][2] = {};
  for (int k = 0; k < 64; ++k) {
    float w0 = wd[k*512 + tid];
    float w1 = wd[k*512 + tid + 256];
#pragma unroll
    for (int r = 0; r < 2; ++r) {
      float dv = dn[r][k];
      accv[0][r] += dv * w0;
      accv[1][r] += dv * w1;
    }
  }

#pragma unroll
  for (int half = 0; half < 2; ++half) {
    int n = tid + half*256;
#pragma unroll
    for (int r = 0; r < 2; ++r) {
      long row = r0 + r;
      const float* gg = e.gate + row*2048;
      float fv = gg[n], iv = gg[512+n], ov = gg[1024+n], cb = gg[1536+n];
      if (e.gate2) {
        const float* g2 = e.gate2 + row*2048;
        fv += g2[n]; iv += g2[512+n]; ov += g2[1024+n]; cb += g2[1536+n];
      }
      if (e.gate3) {
        const float* g3 = e.gate3 + row*2048;
        fv += g3[n]; iv += g3[512+n]; ov += g3[1024+n]; cb += g3[1536+n];
      }
      if (e.xbf) {
        const bf16* xg = (const bf16*)e.xg + row*XW;
        fv += __bfloat162float(xg[n]);      iv += __bfloat162float(xg[512+n]);
        ov += __bfloat162float(xg[1024+n]); cb += __bfloat162float(xg[1536+n]);
      } else {
        const float* xg = (const float*)e.xg + row*XW;
        fv += xg[n]; iv += xg[512+n]; ov += xg[1024+n]; cb += xg[1536+n];
      }
      fv = sigm(fv); iv = sigm(iv); ov = sigm(ov); cb = ftanh(cb);
      float cv = fv * e.c[row*512 + n] + iv * cb + ftanh(accv[half][r]);
      e.c[row*512 + n] = cv;
      e.hout[row*LDH + n] = __float2bfloat16(ov * ftanh(cv));
    }
  }
}

// ---------------- setup kernels
__global__ void k_tpose(const float* __restrict__ src, long srow,
                        bf16* __restrict__ dst, int K, long total)
{
  long idx = (long)blockIdx.x * 256 + threadIdx.x;
  if (idx >= total) return;
  long n = idx / K;
  long k = idx - n * K;
  dst[idx] = __float2bfloat16(src[k * srow + n]);
}

__global__ void k_xconv(const float* __restrict__ x, bf16* __restrict__ xb)
{
  long i = (long)blockIdx.x * 256 + threadIdx.x;
  if (i >= (long)TT*BB*CC) return;
  int cc = (int)(i & 511);
  long r = i >> 9;
  int t = (int)(r / BB), b = (int)(r - (long)t*BB);
  xb[i] = __float2bfloat16(x[((long)b*TT + t)*CC + cc]);
}

__global__ void k_bias(const float* b0,const float* b1,const float* b2,
                       const float* b3,const float* b4,const float* b5,
                       float* out)
{
  int i = blockIdx.x*256 + threadIdx.x;
  if (i < 2048)      out[i] = b0[i] + b1[i];
  else if (i < 4096) out[i] = b2[i-2048] + b3[i-2048];
  else if (i < 6144) out[i] = b4[i-4096] + b5[i-4096];
}

__global__ void k_dinit(const float* __restrict__ keys, float* __restrict__ d)
{
  int i = blockIdx.x*256 + threadIdx.x;
  if (i < 3*BB*KK) d[i] = keys[i % (BB*KK)];
}

// ---------------- host
extern "C" void kernel_launch(void* const* d_in, const int* in_sizes, int n_in,
                              void* d_out, int out_size, void* d_ws, size_t ws_size,
                              hipStream_t stream)
{
  const float* inputs    = (const float*)d_in[0];
  const float* init_keys = (const float*)d_in[1];
  const float* wx_w[3] = {(const float*)d_in[2],  (const float*)d_in[8],  (const float*)d_in[14]};
  const float* wx_b[3] = {(const float*)d_in[3],  (const float*)d_in[9],  (const float*)d_in[15]};
  const float* wh_w[3] = {(const float*)d_in[4],  (const float*)d_in[10], (const float*)d_in[16]};
  const float* wh_b[3] = {(const float*)d_in[5],  (const float*)d_in[11], (const float*)d_in[17]};
  const float* wr_w[3] = {(const float*)d_in[6],  (const float*)d_in[12], (const float*)d_in[18]};
  const float* wl_w[3] = {(const float*)d_in[7],  (const float*)d_in[13], (const float*)d_in[19]};
  const float* wd_w   = (const float*)d_in[20];
  const float* proj_w = (const float*)d_in[21];
  const float* proj_b = (const float*)d_in[22];
  float* out = (float*)d_out;

  char* wsp = (char*)d_ws;
  size_t used = 0;
  auto alloc = [&](size_t bytes) {
    char* p = wsp + used;
    used += (bytes + 255) & ~(size_t)255;
    return p;
  };
  bf16* xb    = (bf16*)alloc((size_t)TT*BB*CC*2);        // [t][b][c] = [28160][512]
  bf16* BXT   = (bf16*)alloc((size_t)6400*512*2);        // x-driven  B^T (padded)
  bf16* BG0T  = (bf16*)alloc((size_t)6400*512*2);        // h0-driven B^T (padded)
  bf16* BG1T  = (bf16*)alloc((size_t)4352*512*2);        // h1-driven B^T (padded)
  bf16* BG2T  = (bf16*)alloc((size_t)2048*512*2);        // h2-driven B^T
  bf16* projT = (bf16*)alloc((size_t)512*1536*2);
  bf16* HallR = (bf16*)alloc((size_t)BB*NHS*1536*2);     // h ring [b][slot][3*512]
  float* accg = (float*)alloc((size_t)4*3*BB*2048*4);    // [slot][l][b][2048]
  float* accr = (float*)alloc((size_t)4*3*BB*64*4);      // [slot][l][b][64]
  float* ubuf = (float*)alloc((size_t)4*2*BB*64*4);      // [slot][j][b][64]
  float* whb1 = (float*)alloc((size_t)2*BB*2048*4);      // Wh1*h1 ring
  float* whb2 = (float*)alloc((size_t)2*BB*2048*4);      // Wh2*h2 ring
  float* g2b  = (float*)alloc((size_t)2*BB*2048*4);      // Wx2[h1-part]*h1 ring (was += into accg)
  float* cbuf = (float*)alloc((size_t)3*BB*DD*4);
  float* dbuf = (float*)alloc((size_t)3*BB*KK*4);
  float* biasg= (float*)alloc((size_t)3*2048*4);
  float* dump = (float*)alloc((size_t)BB*128*4);         // pad-column sink

  // x-ring: ping-pong of NCH steps; fp32 if it fits (ws >= ~248 MB), else bf16
  // (bf16 variant always fits: base 143 MB + 50 MB <= 199 MB lower bound on ws).
  const size_t x32 = (size_t)NXS*512*XW*4;
  const size_t x16 = (size_t)NXS*512*XW*2;
  int plan; char* xring;
  if (used + x32 <= ws_size) { plan = 0; xring = alloc(x32); }
  else                       { plan = 1; xring = alloc(x16); }
  if (used > ws_size) return;

  const long SZG = (long)BB*2048;
  const long SZR = (long)BB*64;

  auto slotg = [&](int s, int l){ return accg + (long)((s&3)*3+l)*SZG; };
  auto slotr = [&](int s, int l){ return accr + (long)((s&3)*3+l)*SZR; };
  auto slotu = [&](int s, int j){ return ubuf + (long)((s&3)*2+j)*SZR; };
  auto slotw1= [&](int s){ return whb1 + (long)(s&1)*SZG; };
  auto slotw2= [&](int s){ return whb2 + (long)(s&1)*SZG; };
  auto hb    = [&](int s){ return HallR + (long)(s % NHS)*1536; };
  auto xrow  = [&](int s){ return (long)((((s>>2)&1)*NCH + (s&3))*512); };

  // ---- setup
  {
    long tot = (long)TT*BB*CC;
    k_xconv<<<dim3((tot + 255)/256), 256, 0, stream>>>(inputs, xb);
  }
  hipMemsetAsync(BXT,  0, (size_t)6400*512*2, stream);
  hipMemsetAsync(BG0T, 0, (size_t)6400*512*2, stream);
  hipMemsetAsync(BG1T, 0, (size_t)4352*512*2, stream);

  auto tp = [&](const float* src, long row_off, long srow, bf16* dstbase, long colbase, int N, int K){
    long total = (long)N*K;
    k_tpose<<<dim3((total + 255)/256), 256, 0, stream>>>(src + row_off*srow, srow, dstbase + colbase*K, K, total);
  };
  // BXT cols: [Wx0|Wr0|Wx1|Wr1|Wx2|Wr2|pad]
  tp(wx_w[0],0,2048, BXT,0,2048,512);   tp(wr_w[0],0,64, BXT,2048,64,512);
  tp(wx_w[1],0,2048, BXT,2112,2048,512);tp(wr_w[1],0,64, BXT,4160,64,512);
  tp(wx_w[2],0,2048, BXT,4224,2048,512);tp(wr_w[2],0,64, BXT,6272,64,512);
  // BG0T cols: [Wx1.h0|Wr1.h0|Wx2.h0|Wr2.h0|Wh0|Wl0|pad]
  tp(wx_w[1],512,2048, BG0T,0,2048,512);   tp(wr_w[1],512,64, BG0T,2048,64,512);
  tp(wx_w[2],512,2048, BG0T,2112,2048,512);tp(wr_w[2],512,64, BG0T,4160,64,512);
  tp(wh_w[0],0,2048,   BG0T,4224,2048,512);tp(wl_w[0],0,64,   BG0T,6272,64,512);
  // BG1T cols: [Wx2.h1|Wr2.h1|Wh1|Wl1|pad]
  tp(wx_w[2],1024,2048, BG1T,0,2048,512);  tp(wr_w[2],1024,64, BG1T,2048,64,512);
  tp(wh_w[1],0,2048,    BG1T,2112,2048,512);tp(wl_w[1],0,64,   BG1T,4160,64,512);
  tp(wh_w[2],0,2048, BG2T,0,2048,512);
  tp(proj_w,0,512, projT,0,512,1536);

  k_bias<<<dim3(24),256,0,stream>>>(wx_b[0],wh_b[0],wx_b[1],wh_b[1],wx_b[2],wh_b[2], biasg);
  hipMemsetAsync(ubuf, 0, (size_t)4*2*BB*64*4, stream);
  hipMemsetAsync(whb1, 0, (size_t)2*SZG*4, stream);
  hipMemsetAsync(whb2, 0, (size_t)2*SZG*4, stream);
  hipMemsetAsync(cbuf, 0, (size_t)3*BB*DD*4, stream);
  hipMemsetAsync(accg, 0, (size_t)SZG*4, stream);   // slotg(0,0): E0(0)'s h-part (h(-1)=0)
  k_dinit<<<dim3((3*BB*KK + 255)/256),256,0,stream>>>(init_keys, dbuf);

  // ---- pipelined recurrence.
  // A(t) = {E0(t),E1(t-1),E2(t-2)}
  // B(t) = {xchunk(t+2..t+5) if (t+2)%4==0, G0(t), G1(t-1), G2(t-2), proj(t-2)}
  for (int t = -2; t <= TT + 1; ++t) {
    // ----- A phase
    CArgs ca{}; ca.n = 0;
    auto addE = [&](int s, int l){
      CellDesc& e = ca.e[ca.n++];
      long ro = xrow(s)*XW + (long)l*2112;
      if (plan == 0) {
        e.xg = (void*)((float*)xring + ro);
        e.xr = (void*)((float*)xring + ro + 2048);
        e.xbf = 0;
      } else {
        e.xg = (void*)((bf16*)xring + ro);
        e.xr = (void*)((bf16*)xring + ro + 2048);
        e.xbf = 1;
      }
      e.gr = (l >= 1) ? slotr(s,l) : nullptr;
      e.gate = slotg(s,l);
      e.gate2 = (l==1) ? slotw1(s) : (l==2) ? slotw2(s) : nullptr;
      e.gate3 = (l==2) ? (g2b + (long)(s&1)*SZG) : nullptr;
      e.u0 = (l>=1) ? slotu(s-1,0) : nullptr;
      e.u1 = (l>=2) ? slotu(s-1,1) : nullptr;
      e.c = cbuf + (long)l*BB*DD; e.d = dbuf + (long)l*BB*KK;
      e.hout = hb(s) + (long)l*512;
    };
    if (t   >= 0 && t   < TT) addE(t,   0);
    if (t-1 >= 0 && t-1 < TT) addE(t-1, 1);
    if (t-2 >= 0 && t-2 < TT) addE(t-2, 2);
    if (ca.n)
      cell_batched<<<dim3(256, ca.n), 256, 0, stream>>>(ca, wd_w);

    // ----- B phase
    GArgs ga{}; ga.ng = 0;
    int cursor = 0;
    auto addG = [&](const bf16* A, long lda, const bf16* Bm, long ldb,
                    int mtiles, int ntiles, int order, int Kd, SegList sl){
      GDesc& g = ga.g[ga.ng++];
      g.A = A; g.lda = lda; g.B = Bm; g.ldb = ldb;
      g.mtiles = mtiles; g.ntiles = ntiles; g.tile_beg = cursor; g.order = order; g.K = Kd;
      cursor += mtiles * ntiles;
      g.segs = sl;
    };
    if (t+2 >= 0 && t+2 < TT && ((t+2) & (NCH-1)) == 0) {  // x-chunk for steps [t+2, t+2+NCH)
      int t0 = t+2;
      int steps = (TT - t0 < NCH) ? (TT - t0) : NCH;
      SegList sl{}; sl.n = 6;
      if (plan == 0) {
        float* x0 = (float*)xring + (long)(((t0>>2)&1)*NCH*512)*XW;
        sl.s[0] = { x0,      XW,    0, 0, biasg + 0    };
        sl.s[1] = { x0+2048, XW, 2048, 0, nullptr      };
        sl.s[2] = { x0+2112, XW, 2112, 0, biasg + 2048 };
        sl.s[3] = { x0+4160, XW, 4160, 0, nullptr      };
        sl.s[4] = { x0+4224, XW, 4224, 0, biasg + 4096 };
        sl.s[5] = { x0+6272, XW, 6272, 0, nullptr      };
      } else {
        bf16* x0 = (bf16*)xring + (long)(((t0>>2)&1)*NCH*512)*XW;
        sl.s[0] = { x0,      XW,    0, 2, biasg + 0    };
        sl.s[1] = { x0+2048, XW, 2048, 2, nullptr      };
        sl.s[2] = { x0+2112, XW, 2112, 2, biasg + 2048 };
        sl.s[3] = { x0+4160, XW, 4160, 2, nullptr      };
        sl.s[4] = { x0+4224, XW, 4224, 2, biasg + 4096 };
        sl.s[5] = { x0+6272, XW, 6272, 2, nullptr      };
      }
      addG(xb + (long)t0*512*512, 512, BXT, 512, steps*8, 50, 2, 512, sl);
    }
    if (t >= 0 && t < TT) {      // G0(t): h0-driven
      int s = t;
      SegList sl{}; sl.n = 7;
      sl.s[0] = { slotg(s,1),   2048,    0, 0, nullptr };
      sl.s[1] = { slotr(s,1),     64, 2048, 0, nullptr };
      sl.s[2] = { slotg(s,2),   2048, 2112, 0, nullptr };
      sl.s[3] = { slotr(s,2),     64, 4160, 0, nullptr };
      sl.s[4] = { slotg(s+1,0), 2048, 4224, 0, nullptr };  // Wh0 -> gate0(t+1)
      sl.s[5] = { slotu(s,0),     64, 6272, 0, nullptr };  // u0 = h0@Wl0
      sl.s[6] = { dump,          128, 6336, 0, nullptr };
      addG(hb(s), LDH, BG0T, 512, 8, 50, 1, 512, sl);
    }
    if (t-1 >= 0 && t-1 < TT) {  // G1(t-1): h1-driven
      int s = t-1;
      SegList sl{}; sl.n = 5;
      sl.s[0] = { g2b + (long)(s&1)*SZG, 2048, 0, 0, nullptr };  // Wx2[h1] -> gate3 ring (no RMW)
      sl.s[1] = { slotr(s,2),     64, 2048, 1, nullptr };        // Wr2[h1] += (tiny)
      sl.s[2] = { slotw1(s+1),  2048, 2112, 0, nullptr };        // Wh1*h1(s) -> whb1 ring
      sl.s[3] = { slotu(s,1),     64, 4160, 0, nullptr };        // u1 = h1@Wl1
      sl.s[4] = { dump,          128, 4224, 0, nullptr };
      addG(hb(s) + 512, LDH, BG1T, 512, 8, 34, 1, 512, sl);
    }
    if (t-2 >= 0 && t-2 <= TT-2) {  // G2(t-2): h2-driven
      int s = t-2;
      SegList sl{}; sl.n = 1;
      sl.s[0] = { slotw2(s+1), 2048, 0, 0, nullptr };      // Wh2*h2(s) -> whb2 ring
      addG(hb(s) + 1024, LDH, BG2T, 512, 8, 16, 1, 512, sl);
    }
    if (t-2 >= 0 && t-2 < TT) {  // proj(t-2): all three h layers of step s are final
      int s = t-2;
      SegList sl{}; sl.n = 1;
      sl.s[0] = { out + (long)s*512, (long)TT*512, 0, 0, proj_b };
      addG(hb(s), LDH, projT, 1536, 8, 4, 0, 1536, sl);
    }
    if (cursor) {
      ga.total = cursor; ga.chunk = (cursor + 7) / 8;
      gemm_batched<<<dim3(ga.chunk * 8), 256, 0, stream>>>(ga);
    }
  }
}